// Round 15
// baseline (23.873 us; speedup 1.0000x reference)
//
#include <hip/hip_runtime.h>
#include <math.h>

#define NF   640
#define IMGN 256
#define NPIX (IMGN * IMGN)
#define TEXN 6
#define NV   400
#define TPB  1024           // 16 waves
#define PXW  128            // pixels per block (half a row)
#define NSW  10             // setup waves (640 faces / 64 lanes)
#define NCH  16             // raster slices == waves
#define CHF  64             // faces per setup wave (fully active)

// 512 blocks x 1024 threads, 2 blocks/CU = 32 waves/CU.
// R15: LDS-pipe cuts. (a) projected verts packed float4 -> 1 ds_read_b128
// per vertex gather (was 3 scalar ds_read_b32); (b) fZ {z1,z2} read only
// when the sign gate passes for either pixel.
//
// CORRECTNESS CONTRACT (bit-exact vs numpy f32 ref, verified R2-R14):
//  - fp contract OFF, true IEEE '/', identical op order on decision path
//  - per-vertex division == per-face-vertex division (same bits)
//  - sign gate == post-division w>=0 test (IEEE sign rules)
//  - bbox cull conservative (pad (ext+1)*1e-6 >> ~ext*2^-23 accept slack);
//    degenerate faces never listed == det_ok mask
//  - ordered-partition slices + strict '<' == jnp.argmin first-occurrence
//  - packing & conditional loads change no arithmetic
__global__ __launch_bounds__(TPB) void render_kernel(
    const float* __restrict__ verts,   // 400*3 f32
    const int*   __restrict__ faces,   // 640*3 i32
    const float* __restrict__ tex,     // 640*6*6*6*3 f32
    float* __restrict__ out)           // 3*65536 f32 (planar CHW)
{
#pragma clang fp contract(off)
    __shared__ float4 sV4[NV];                    //  6400 B {px,py,z0,-}
    __shared__ float4 fA[NF];                     // 10240 B {v0x,v0y,ex,ey}
    __shared__ float4 fB[NF];                     // 10240 B {dx,dy,det,z0}
    __shared__ float2 fZ[NF];                     //  5120 B {z1,z2}
    __shared__ unsigned short sListW[NSW][CHF];   //  1280 B
    __shared__ unsigned short sMerged[NF];        //  1280 B
    __shared__ int   sCnt[NSW];                   //    40 B
    __shared__ float rD[NCH][PXW];                //  8192 B
    __shared__ int   rI[NCH][PXW];                //  8192 B => ~49.8 KB

    const float EPSf = 1e-8f;
    const int tid  = (int)threadIdx.x;
    const int wid  = tid >> 6;
    const int lane = tid & 63;
    const int p0   = (int)blockIdx.x * PXW;
    const int pi   = p0 >> 8;          // row (uniform per block)
    const int pj0  = p0 & (IMGN - 1);  // first col (0 or 128)

    const float by    = -(((pi + 0.5f) / (float)IMGN) * 2.0f - 1.0f);
    const float bxmin = ((pj0 + 0.5f) / (float)IMGN) * 2.0f - 1.0f;
    const float bxmax = ((pj0 + (PXW - 1) + 0.5f) / (float)IMGN) * 2.0f - 1.0f;

    // ---- front-loaded global reads: faces idx (regs) + verts, HBM
    //      latencies overlapped (R14) ----
    int ia = 0, ib = 0, ic = 0;
    if (wid < NSW) {
        int f = tid;                   // 64*wid + lane, all lanes active
        ia = faces[3 * f + 0];
        ib = faces[3 * f + 1];
        ic = faces[3 * f + 2];
    }
    if (tid < NV) {
        float x = verts[3 * tid], y = verts[3 * tid + 1], z = verts[3 * tid + 2];
        float z0 = z + 2.0f;
        float den = z0 * 1.0f + EPSf;   // same op order as reference
        sV4[tid] = make_float4(x / den, y / den, z0, 0.0f);
    }
    __syncthreads();

    // ---- phase 1: setup + cull, waves 0-9 fully active (f = tid),
    //      one ds_read_b128 per vertex gather ----
    if (wid < NSW) {
        int f = tid;
        float4 v0 = sV4[ia];
        float4 v1 = sV4[ib];
        float4 v2 = sV4[ic];
        float px0 = v0.x, py0 = v0.y, z0 = v0.z;
        float px1 = v1.x, py1 = v1.y, z1 = v1.z;
        float px2 = v2.x, py2 = v2.y, z2 = v2.z;

        float dx = px1 - px0, dy = py1 - py0;
        float ex = px2 - px0, ey = py2 - py0;
        float det = dx * ey - dy * ex;
        bool ok = fabsf(det) > 1e-8f;

        fA[f] = make_float4(px0, py0, ex, ey);
        fB[f] = make_float4(dx, dy, ok ? det : 1.0f, z0);
        fZ[f] = make_float2(z1, z2);

        bool pred = false;
        if (ok) {
            float xmin = fminf(px0, fminf(px1, px2));
            float xmax = fmaxf(px0, fmaxf(px1, px2));
            float ymin = fminf(py0, fminf(py1, py2));
            float ymax = fmaxf(py0, fmaxf(py1, py2));
            float padx = (fmaxf(fabsf(xmin), fabsf(xmax)) + 1.0f) * 1e-6f;
            float pady = (fmaxf(fabsf(ymin), fabsf(ymax)) + 1.0f) * 1e-6f;
            pred = (ymin - pady <= by)    && (ymax + pady >= by) &&
                   (xmin - padx <= bxmax) && (xmax + padx >= bxmin);
        }
        unsigned long long m = __ballot(pred);
        if (pred)
            sListW[wid][(int)__popcll(m & ((1ull << lane) - 1ull))] =
                (unsigned short)f;
        if (lane == 0) sCnt[wid] = (int)__popcll(m);
    }
    __syncthreads();

    // ---- phase 1b: concatenate lists (ascending), balanced slices ----
    int base = 0, total = 0;
    #pragma unroll
    for (int c = 0; c < NSW; ++c) {
        int cc = sCnt[c];
        if (c < wid) base += cc;
        total += cc;
    }
    if (wid < NSW) {
        int cnt = sCnt[wid];
        for (int i = lane; i < cnt; i += 64)
            sMerged[base + i] = sListW[wid][i];
    }
    __syncthreads();

    // ---- phase 2: raster balanced slice, 2 pixels per lane; fZ read
    //      only when a gate passes ----
    const float ppx0 = ((pj0 + lane      + 0.5f) / (float)IMGN) * 2.0f - 1.0f;
    const float ppx1 = ((pj0 + lane + 64 + 0.5f) / (float)IMGN) * 2.0f - 1.0f;

    const int per = (total + NCH - 1) >> 4;
    const int kb  = wid * per;
    const int ke  = (kb + per < total) ? (kb + per) : total;

    float best0 = 1e30f, best1 = 1e30f;
    int   bi0 = -1,      bi1 = -1;

    for (int k = kb; k < ke; ++k) {
        int f = (int)sMerged[k];
        float4 a = fA[f];             // v0x v0y ex ey
        float4 b = fB[f];             // dx dy det z0
        float qy = by - a.y;          // row-uniform
        float t1 = qy * a.z;          // qy*ex (same mul tree, bit-exact R10)
        float t2 = b.x * qy;          // dx*qy
        bool detpos = (b.z > 0.0f);

        float qx0 = ppx0 - a.x;
        float n10 = qx0 * a.w - t1;
        float n20 = t2 - b.y * qx0;
        bool pass0 = detpos ? (n10 >= 0.0f && n20 >= 0.0f)
                            : (n10 <= 0.0f && n20 <= 0.0f);

        float qx1 = ppx1 - a.x;
        float n11 = qx1 * a.w - t1;
        float n21 = t2 - b.y * qx1;
        bool pass1 = detpos ? (n11 >= 0.0f && n21 >= 0.0f)
                            : (n11 <= 0.0f && n21 <= 0.0f);

        if (pass0 || pass1) {
            float2 zz = fZ[f];        // z1 z2 — only on gate pass
            if (pass0) {
                float w1 = n10 / b.z;
                float w2 = n20 / b.z;
                float w0 = (1.0f - w1) - w2;
                if (w0 >= 0.0f) {
                    float depth = ((w0 * b.w) + (w1 * zz.x)) + (w2 * zz.y);
                    if (depth > 0.0f && depth < best0) { best0 = depth; bi0 = f; }
                }
            }
            if (pass1) {
                float w1 = n11 / b.z;
                float w2 = n21 / b.z;
                float w0 = (1.0f - w1) - w2;
                if (w0 >= 0.0f) {
                    float depth = ((w0 * b.w) + (w1 * zz.x)) + (w2 * zz.y);
                    if (depth > 0.0f && depth < best1) { best1 = depth; bi1 = f; }
                }
            }
        }
    }

    rD[wid][lane]      = best0;
    rI[wid][lane]      = bi0;
    rD[wid][lane + 64] = best1;
    rI[wid][lane + 64] = bi1;
    __syncthreads();

    // ---- phase 3: tid<128 merge 16 slices; tex loads issued before
    //      lighting (R14) ----
    if (tid < PXW) {
        float bd = rD[0][tid];
        int   fi = rI[0][tid];
        #pragma unroll
        for (int c = 1; c < NCH; ++c) {
            float d = rD[c][tid];
            if (d < bd) { bd = d; fi = rI[c][tid]; }  // slice-ascending, strict <
        }

        int pp = p0 + tid;
        float r = 0.0f, g = 0.0f, b = 0.0f;
        if (fi >= 0) {
            // barycentrics first (LDS, short): identical ops on same bits
            float4 a2 = fA[fi];
            float4 b2 = fB[fi];
            float sx = ((pj0 + tid + 0.5f) / (float)IMGN) * 2.0f - 1.0f;
            float qx = sx - a2.x;
            float qy = by - a2.y;
            float n1 = qx * a2.w - qy * a2.z;
            float n2 = b2.x * qy - b2.y * qx;
            float w1 = n1 / b2.z;
            float w2 = n2 / b2.z;
            float w0 = (1.0f - w1) - w2;

            int i0 = (int)(w0 * (float)TEXN);
            int i1 = (int)(w1 * (float)TEXN);
            int i2 = (int)(w2 * (float)TEXN);
            i0 = i0 < 0 ? 0 : (i0 > TEXN - 1 ? TEXN - 1 : i0);
            i1 = i1 < 0 ? 0 : (i1 > TEXN - 1 ? TEXN - 1 : i1);
            i2 = i2 < 0 ? 0 : (i2 > TEXN - 1 ? TEXN - 1 : i2);
            const float* tp = tex + (size_t)((((fi * TEXN + i0) * TEXN + i1) * TEXN + i2) * 3);
            float t0v = tp[0];         // issue loads now...
            float t1v = tp[1];
            float t2v = tp[2];

            // ...lighting runs while tex loads are in flight
            int ja = faces[3 * fi + 0];
            int jb = faces[3 * fi + 1];
            int jc = faces[3 * fi + 2];
            float ax = verts[3 * ja], ay = verts[3 * ja + 1], az = verts[3 * ja + 2];
            float bx = verts[3 * jb], byv = verts[3 * jb + 1], bz = verts[3 * jb + 2];
            float cx = verts[3 * jc], cy = verts[3 * jc + 1], cz = verts[3 * jc + 2];
            float e1x = bx - ax, e1y = byv - ay, e1z = bz - az;
            float e2x = cx - ax, e2y = cy - ay, e2z = cz - az;
            float nx = e1y * e2z - e1z * e2y;
            float ny = e1z * e2x - e1x * e2z;
            float nz = e1x * e2y - e1y * e2x;
            float nn = sqrtf((nx * nx + ny * ny) + nz * nz) + EPSf;
            float diff = nz / nn;
            diff = diff > 0.0f ? diff : 0.0f;
            float light = 0.5f + 0.5f * diff;

            r = tanhf(t0v) * light;
            g = tanhf(t1v) * light;
            b = tanhf(t2v) * light;
        }
        out[pp]            = r;
        out[NPIX + pp]     = g;
        out[2 * NPIX + pp] = b;
    }
}

extern "C" void kernel_launch(void* const* d_in, const int* in_sizes, int n_in,
                              void* d_out, int out_size, void* d_ws, size_t ws_size,
                              hipStream_t stream) {
    (void)in_sizes; (void)n_in; (void)d_ws; (void)ws_size; (void)out_size;
    const float* verts = (const float*)d_in[0];
    const int*   faces = (const int*)d_in[1];
    const float* tex   = (const float*)d_in[2];
    float*       out   = (float*)d_out;
    render_kernel<<<NPIX / PXW, TPB, 0, stream>>>(verts, faces, tex, out);
}

// Round 16
// 21.992 us; speedup vs baseline: 1.0856x; 1.0856x over previous
//
#include <hip/hip_runtime.h>
#include <math.h>

#define NF   640
#define IMGN 256
#define NPIX (IMGN * IMGN)
#define TEXN 6
#define NV   400
#define TPB  1024           // 16 waves
#define PXW  128            // pixels per block (half a row)
#define NSW  10             // setup waves (640 faces / 64 lanes)
#define NCH  16             // raster slices == waves
#define CHF  64             // faces per setup wave (fully active)

// R16 = exact revert to R14 (best verified: 22.2 us, absmax 0.0).
// R15's LDS packing (b128 random gathers) and conditional fZ both
// regressed; scalar b32 gathers + unconditional b64 record reads win.
//
// 512 blocks x 1024 threads, 2 blocks/CU = 32 waves/CU.
// (a) faces-index loads issued BEFORE the verts-projection phase so both
// cold-HBM round trips overlap; (b) phase-3 texture loads issued before
// the lighting computation so the scattered gather hides under ~400 cyc
// of VALU.
//
// CORRECTNESS CONTRACT (bit-exact vs numpy f32 ref, verified R2-R15):
//  - fp contract OFF, true IEEE '/', identical op order on decision path
//  - per-vertex division == per-face-vertex division (same bits)
//  - sign gate == post-division w>=0 test (IEEE sign rules)
//  - bbox cull conservative (pad (ext+1)*1e-6 >> ~ext*2^-23 accept slack);
//    degenerate faces never listed == det_ok mask
//  - ordered-partition slices + strict '<' == jnp.argmin first-occurrence
//  - winner-only lighting: identical expression order on identical bits
__global__ __launch_bounds__(TPB) void render_kernel(
    const float* __restrict__ verts,   // 400*3 f32
    const int*   __restrict__ faces,   // 640*3 i32
    const float* __restrict__ tex,     // 640*6*6*6*3 f32
    float* __restrict__ out)           // 3*65536 f32 (planar CHW)
{
#pragma clang fp contract(off)
    __shared__ float  sPX[NV], sPY[NV], sZ[NV];   //  4800 B
    __shared__ float4 fA[NF];                     // 10240 B {v0x,v0y,ex,ey}
    __shared__ float4 fB[NF];                     // 10240 B {dx,dy,det,z0}
    __shared__ float2 fZ[NF];                     //  5120 B {z1,z2}
    __shared__ unsigned short sListW[NSW][CHF];   //  1280 B
    __shared__ unsigned short sMerged[NF];        //  1280 B
    __shared__ int   sCnt[NSW];                   //    40 B
    __shared__ float rD[NCH][PXW];                //  8192 B
    __shared__ int   rI[NCH][PXW];                //  8192 B => ~49.4 KB

    const float EPSf = 1e-8f;
    const int tid  = (int)threadIdx.x;
    const int wid  = tid >> 6;
    const int lane = tid & 63;
    const int p0   = (int)blockIdx.x * PXW;
    const int pi   = p0 >> 8;          // row (uniform per block)
    const int pj0  = p0 & (IMGN - 1);  // first col (0 or 128)

    const float by    = -(((pi + 0.5f) / (float)IMGN) * 2.0f - 1.0f);
    const float bxmin = ((pj0 + 0.5f) / (float)IMGN) * 2.0f - 1.0f;
    const float bxmax = ((pj0 + (PXW - 1) + 0.5f) / (float)IMGN) * 2.0f - 1.0f;

    // ---- front-loaded global reads: faces idx (regs) + verts, issued
    //      together so their HBM latencies overlap ----
    int ia = 0, ib = 0, ic = 0;
    if (wid < NSW) {
        int f = tid;                   // 64*wid + lane, all lanes active
        ia = faces[3 * f + 0];
        ib = faces[3 * f + 1];
        ic = faces[3 * f + 2];
    }
    if (tid < NV) {
        float x = verts[3 * tid], y = verts[3 * tid + 1], z = verts[3 * tid + 2];
        float z0 = z + 2.0f;
        float den = z0 * 1.0f + EPSf;   // same op order as reference
        sPX[tid] = x / den;
        sPY[tid] = y / den;
        sZ[tid]  = z0;
    }
    __syncthreads();

    // ---- phase 1: setup + cull, waves 0-9 fully active (f = tid) ----
    if (wid < NSW) {
        int f = tid;
        float px0 = sPX[ia], py0 = sPY[ia], z0 = sZ[ia];
        float px1 = sPX[ib], py1 = sPY[ib], z1 = sZ[ib];
        float px2 = sPX[ic], py2 = sPY[ic], z2 = sZ[ic];

        float dx = px1 - px0, dy = py1 - py0;
        float ex = px2 - px0, ey = py2 - py0;
        float det = dx * ey - dy * ex;
        bool ok = fabsf(det) > 1e-8f;

        fA[f] = make_float4(px0, py0, ex, ey);
        fB[f] = make_float4(dx, dy, ok ? det : 1.0f, z0);
        fZ[f] = make_float2(z1, z2);

        bool pred = false;
        if (ok) {
            float xmin = fminf(px0, fminf(px1, px2));
            float xmax = fmaxf(px0, fmaxf(px1, px2));
            float ymin = fminf(py0, fminf(py1, py2));
            float ymax = fmaxf(py0, fmaxf(py1, py2));
            float padx = (fmaxf(fabsf(xmin), fabsf(xmax)) + 1.0f) * 1e-6f;
            float pady = (fmaxf(fabsf(ymin), fabsf(ymax)) + 1.0f) * 1e-6f;
            pred = (ymin - pady <= by)    && (ymax + pady >= by) &&
                   (xmin - padx <= bxmax) && (xmax + padx >= bxmin);
        }
        unsigned long long m = __ballot(pred);
        if (pred)
            sListW[wid][(int)__popcll(m & ((1ull << lane) - 1ull))] =
                (unsigned short)f;
        if (lane == 0) sCnt[wid] = (int)__popcll(m);
    }
    __syncthreads();

    // ---- phase 1b: concatenate lists (ascending), balanced slices ----
    int base = 0, total = 0;
    #pragma unroll
    for (int c = 0; c < NSW; ++c) {
        int cc = sCnt[c];
        if (c < wid) base += cc;
        total += cc;
    }
    if (wid < NSW) {
        int cnt = sCnt[wid];
        for (int i = lane; i < cnt; i += 64)
            sMerged[base + i] = sListW[wid][i];
    }
    __syncthreads();

    // ---- phase 2: raster balanced slice, 2 pixels per lane ----
    const float ppx0 = ((pj0 + lane      + 0.5f) / (float)IMGN) * 2.0f - 1.0f;
    const float ppx1 = ((pj0 + lane + 64 + 0.5f) / (float)IMGN) * 2.0f - 1.0f;

    const int per = (total + NCH - 1) >> 4;
    const int kb  = wid * per;
    const int ke  = (kb + per < total) ? (kb + per) : total;

    float best0 = 1e30f, best1 = 1e30f;
    int   bi0 = -1,      bi1 = -1;

    for (int k = kb; k < ke; ++k) {
        int f = (int)sMerged[k];
        float4 a = fA[f];             // v0x v0y ex ey
        float4 b = fB[f];             // dx dy det z0
        float2 zz = fZ[f];            // z1 z2
        float qy = by - a.y;          // row-uniform
        float t1 = qy * a.z;          // qy*ex (same mul tree, bit-exact R10)
        float t2 = b.x * qy;          // dx*qy
        bool detpos = (b.z > 0.0f);

        {   // pixel 0
            float qx = ppx0 - a.x;
            float n1 = qx * a.w - t1;
            float n2 = t2 - b.y * qx;
            bool pass = detpos ? (n1 >= 0.0f && n2 >= 0.0f)
                               : (n1 <= 0.0f && n2 <= 0.0f);
            if (pass) {
                float w1 = n1 / b.z;
                float w2 = n2 / b.z;
                float w0 = (1.0f - w1) - w2;
                if (w0 >= 0.0f) {
                    float depth = ((w0 * b.w) + (w1 * zz.x)) + (w2 * zz.y);
                    if (depth > 0.0f && depth < best0) { best0 = depth; bi0 = f; }
                }
            }
        }
        {   // pixel 1
            float qx = ppx1 - a.x;
            float n1 = qx * a.w - t1;
            float n2 = t2 - b.y * qx;
            bool pass = detpos ? (n1 >= 0.0f && n2 >= 0.0f)
                               : (n1 <= 0.0f && n2 <= 0.0f);
            if (pass) {
                float w1 = n1 / b.z;
                float w2 = n2 / b.z;
                float w0 = (1.0f - w1) - w2;
                if (w0 >= 0.0f) {
                    float depth = ((w0 * b.w) + (w1 * zz.x)) + (w2 * zz.y);
                    if (depth > 0.0f && depth < best1) { best1 = depth; bi1 = f; }
                }
            }
        }
    }

    rD[wid][lane]      = best0;
    rI[wid][lane]      = bi0;
    rD[wid][lane + 64] = best1;
    rI[wid][lane + 64] = bi1;
    __syncthreads();

    // ---- phase 3: tid<128 merge 16 slices; tex loads issued BEFORE
    //      lighting so the scattered gather hides under the VALU ----
    if (tid < PXW) {
        float bd = rD[0][tid];
        int   fi = rI[0][tid];
        #pragma unroll
        for (int c = 1; c < NCH; ++c) {
            float d = rD[c][tid];
            if (d < bd) { bd = d; fi = rI[c][tid]; }  // slice-ascending, strict <
        }

        int pp = p0 + tid;
        float r = 0.0f, g = 0.0f, b = 0.0f;
        if (fi >= 0) {
            // barycentrics first (LDS, short): identical ops on same bits
            float4 a2 = fA[fi];
            float4 b2 = fB[fi];
            float sx = ((pj0 + tid + 0.5f) / (float)IMGN) * 2.0f - 1.0f;
            float qx = sx - a2.x;
            float qy = by - a2.y;
            float n1 = qx * a2.w - qy * a2.z;
            float n2 = b2.x * qy - b2.y * qx;
            float w1 = n1 / b2.z;
            float w2 = n2 / b2.z;
            float w0 = (1.0f - w1) - w2;

            int i0 = (int)(w0 * (float)TEXN);
            int i1 = (int)(w1 * (float)TEXN);
            int i2 = (int)(w2 * (float)TEXN);
            i0 = i0 < 0 ? 0 : (i0 > TEXN - 1 ? TEXN - 1 : i0);
            i1 = i1 < 0 ? 0 : (i1 > TEXN - 1 ? TEXN - 1 : i1);
            i2 = i2 < 0 ? 0 : (i2 > TEXN - 1 ? TEXN - 1 : i2);
            const float* tp = tex + (size_t)((((fi * TEXN + i0) * TEXN + i1) * TEXN + i2) * 3);
            float t0v = tp[0];         // issue loads now...
            float t1v = tp[1];
            float t2v = tp[2];

            // ...lighting runs while tex loads are in flight
            int ja = faces[3 * fi + 0];
            int jb = faces[3 * fi + 1];
            int jc = faces[3 * fi + 2];
            float ax = verts[3 * ja], ay = verts[3 * ja + 1], az = verts[3 * ja + 2];
            float bx = verts[3 * jb], byv = verts[3 * jb + 1], bz = verts[3 * jb + 2];
            float cx = verts[3 * jc], cy = verts[3 * jc + 1], cz = verts[3 * jc + 2];
            float e1x = bx - ax, e1y = byv - ay, e1z = bz - az;
            float e2x = cx - ax, e2y = cy - ay, e2z = cz - az;
            float nx = e1y * e2z - e1z * e2y;
            float ny = e1z * e2x - e1x * e2z;
            float nz = e1x * e2y - e1y * e2x;
            float nn = sqrtf((nx * nx + ny * ny) + nz * nz) + EPSf;
            float diff = nz / nn;
            diff = diff > 0.0f ? diff : 0.0f;
            float light = 0.5f + 0.5f * diff;

            r = tanhf(t0v) * light;
            g = tanhf(t1v) * light;
            b = tanhf(t2v) * light;
        }
        out[pp]            = r;
        out[NPIX + pp]     = g;
        out[2 * NPIX + pp] = b;
    }
}

extern "C" void kernel_launch(void* const* d_in, const int* in_sizes, int n_in,
                              void* d_out, int out_size, void* d_ws, size_t ws_size,
                              hipStream_t stream) {
    (void)in_sizes; (void)n_in; (void)d_ws; (void)ws_size; (void)out_size;
    const float* verts = (const float*)d_in[0];
    const int*   faces = (const int*)d_in[1];
    const float* tex   = (const float*)d_in[2];
    float*       out   = (float*)d_out;
    render_kernel<<<NPIX / PXW, TPB, 0, stream>>>(verts, faces, tex, out);
}